// Round 4
// baseline (706.449 us; speedup 1.0000x reference)
//
#include <hip/hip_runtime.h>

typedef float f2 __attribute__((ext_vector_type(2)));

#define DIM   256
#define RANK  64
#define NSEG0 192                 // dim - rank = shortest segment
#define N0    14304               // sum_{j=0}^{63} (192+j) complex pairs per batch
#define NW    8                   // waves per block (scan bands of 8)
#define TILE  8                   // rows per staged trig tile
#define NBUF  3                   // trig tile buffers
#define HSTEP (DIM / 2)           // 128 row-pairs
#define NMACRO 34                 // 34*4 = 136 substeps >= 135
#define ROWB  (65 * 16)           // bytes per trig row: 64 segments + identity col

// Raw barrier without vmcnt drain (R2: neutral vs __syncthreads, kept so the
// theta prefetch can stay in flight). lgkmcnt(0) orders LDS write->bar->read.
#define BAR() asm volatile("s_waitcnt lgkmcnt(0)\n\ts_barrier" ::: "memory")

// Complex Givens-with-phase rotation, 8 packed VOP3P ops, no predication.
// Predication/deposit/dead-row behavior is encoded in the trig VALUES:
//   (ct,st,er,ei) = real trig     -> rotation
//   (1, 0, 1, 0)                  -> V'=A, A'=V      (deposit row, bit-exact)
//   (0,-1, 1, 0)                  -> V'=V, A'=-A     (identity; A never read)
__device__ __forceinline__ void rot_pk(const f2 qts, const f2 qps, f2& V, f2& A)
{
    f2 t1, u, t2, pp, t3, t4;
    // t1 = {ct,ct} * A
    asm("v_pk_mul_f32 %0, %1, %2 op_sel:[0,0] op_sel_hi:[0,1]"
        : "=v"(t1) : "v"(qts), "v"(A));
    // u = -{st,st} * V + t1
    asm("v_pk_fma_f32 %0, %1, %2, %3 op_sel:[1,0,0] op_sel_hi:[1,1,1] neg_lo:[1,0,0] neg_hi:[1,0,0]"
        : "=v"(u) : "v"(qts), "v"(V), "v"(t1));
    // t2 = {ct,ct} * V
    asm("v_pk_mul_f32 %0, %1, %2 op_sel:[0,0] op_sel_hi:[0,1]"
        : "=v"(t2) : "v"(qts), "v"(V));
    // pp = {st,st} * A + t2
    asm("v_pk_fma_f32 %0, %1, %2, %3 op_sel:[1,0,0] op_sel_hi:[1,1,1]"
        : "=v"(pp) : "v"(qts), "v"(A), "v"(t2));
    // t3 = {er,er} * u
    asm("v_pk_mul_f32 %0, %1, %2 op_sel:[0,0] op_sel_hi:[0,1]"
        : "=v"(t3) : "v"(qps), "v"(u));
    // V = {ei,ei} * {u.y, -u.x} + t3        (u * conj(e))
    asm("v_pk_fma_f32 %0, %1, %2, %3 op_sel:[1,1,0] op_sel_hi:[1,0,1] neg_hi:[0,1,0]"
        : "=v"(V) : "v"(qps), "v"(u), "v"(t3));
    // t4 = {er,er} * pp
    asm("v_pk_mul_f32 %0, %1, %2 op_sel:[0,0] op_sel_hi:[0,1]"
        : "=v"(t4) : "v"(qps), "v"(pp));
    // A = {ei,ei} * {-pp.y, pp.x} + t4      (pp * e)
    asm("v_pk_fma_f32 %0, %1, %2, %3 op_sel:[1,1,0] op_sel_hi:[1,0,1] neg_lo:[0,1,0]"
        : "=v"(A) : "v"(qps), "v"(pp), "v"(t4));
}

__global__ __launch_bounds__(64 * NW, NW)
void stiefel_pipe(const float* __restrict__ theta, float* __restrict__ out,
                  long long out_limit)
{
    const int b   = blockIdx.x;
    const int tid = threadIdx.x;
    const int w   = __builtin_amdgcn_readfirstlane(tid >> 6);  // band 0..7 (SGPR)
    const int c   = tid & 63;                                  // column lane

    const float2* tb = (const float2*)theta + (size_t)b * N0;  // (t,p) pairs
    const long long obase = (long long)b * (DIM * RANK);

    // 3*8*65*16 = 24960 B  +  7*2*64*16 = 14336 B  -> 39296 B (4 blocks/CU)
    __shared__ float4 trigT[NBUF][TILE][65];
    __shared__ float4 pipe[NW - 1][2][64];    // [boundary][pair parity][col] = {V0,V1}

    const int jbase = 8 * w;

    f2 A[8];
    #pragma unroll
    for (int k = 0; k < 8; ++k) A[k] = (f2){0.f, 0.f};

    // per-lane trig column byte offsets; identity col 64 for inactive (lane,scan)
    int coff[8];
    #pragma unroll
    for (int k = 0; k < 8; ++k) {
        const int j = jbase + k;
        coff[k] = ((c >= 64 - j) ? j : 64) << 4;
    }

    // staging ownership: thread -> (row rS of tile, segment jS); 512 thr = 8x64
    const int jS   = c;
    const int rS   = w;
    const int offS = NSEG0 * jS + ((jS * (jS - 1)) >> 1);
    const int lenS = NSEG0 + jS;

    // identity column: content never changes, init all buffers once
    if (tid < NBUF * TILE) {
        trigT[tid / TILE][tid % TILE][64] = make_float4(0.f, -1.f, 1.f, 0.f);
    }

    // rowJ generator state (band 0; lane c <-> segment 63-c)
    const int gseg = 63 - c;
    float S = 1.f, Er = 1.f, Ei = 0.f;

    // prefetch theta for tile 0 (row rS < 192 always valid)
    float2 pf = tb[offS + rS];

    const char* ldsT = (const char*)trigT;

    #pragma unroll 1
    for (int Sm = 0; Sm < NMACRO; ++Sm) {
        // ---- stage one 8-row trig tile per macro-step, from prefetched regs ----
        if (Sm < 32) {
            const int i = (Sm << 3) + rS;          // global row this thread stages
            float4 val;
            if (i < lenS) {
                val = make_float4(__cosf(pf.x), __sinf(pf.x),
                                  __cosf(pf.y), __sinf(pf.y));
            } else if (i == lenS) {
                val = make_float4(1.f, 0.f, 1.f, 0.f);     // deposit row
            } else {
                val = make_float4(0.f, -1.f, 1.f, 0.f);    // dead row (identity)
            }
            trigT[Sm % NBUF][rS][jS] = val;
            const int i2 = i + TILE;               // prefetch next tile's theta
            if (i2 < lenS && Sm + 1 < 32) pf = tb[offS + i2];
        }

        #pragma unroll
        for (int u = 0; u < 4; ++u) {
            const int s = (Sm << 2) + u;
            BAR();                                 // the step boundary

            const int q = s - w;                   // this band's row-pair index
            if (q >= 0 && q < HSTEP) {
                const int i0 = q << 1;             // even row of the pair
                const int rowbase =
                    ((((i0 >> 3) % NBUF) * TILE + (i0 & 7))) * ROWB;

                // ---- issue the band-entry value load FIRST (longest chain) ----
                float4 g0, g1, pv;
                if (w == 0) {
                    const char* gp = ldsT + (rowbase + (gseg << 4));
                    g0 = *(const float4*)gp;
                    g1 = *(const float4*)(gp + ROWB);
                } else {
                    pv = pipe[w - 1][q & 1][c];
                }

                // ---- trig software pipeline, 2 scans in flight ----
                const char* rp0 = ldsT + (rowbase + coff[0]);
                const char* rp1 = ldsT + (rowbase + coff[1]);
                float4 c0 = *(const float4*)rp0;          // scan k   row i0
                float4 c1 = *(const float4*)(rp0 + ROWB); // scan k   row i0+1
                float4 d0 = *(const float4*)rp1;          // scan k+1 row i0
                float4 d1 = *(const float4*)(rp1 + ROWB);

                // ---- values entering this band (2 rows) ----
                f2 V0, V1;
                if (w == 0) {
                    {   // row i0
                        const float Fr = Er * g0.z + Ei * g0.w;   // E * conj(e_i)
                        const float Fi = Ei * g0.z - Er * g0.w;
                        const float amp = g0.x * S;
                        V0 = (f2){amp * Fr, amp * Fi};
                        S *= g0.y;
                        const float nEr = Er * g0.z - Ei * g0.w;  // E *= e_i
                        const float nEi = Ei * g0.z + Er * g0.w;
                        Er = nEr; Ei = nEi;
                    }
                    {   // row i0+1
                        const float Fr = Er * g1.z + Ei * g1.w;
                        const float Fi = Ei * g1.z - Er * g1.w;
                        const float amp = g1.x * S;
                        V1 = (f2){amp * Fr, amp * Fi};
                        S *= g1.y;
                        const float nEr = Er * g1.z - Ei * g1.w;
                        const float nEi = Ei * g1.z + Er * g1.w;
                        Er = nEr; Ei = nEi;
                    }
                } else {
                    V0 = (f2){pv.x, pv.y};
                    V1 = (f2){pv.z, pv.w};
                }

                // ---- 8 scans x 2 rows, loads pipelined 2 scans ahead ----
                #pragma unroll
                for (int k = 0; k < 8; ++k) {
                    float4 e0 = c0, e1 = c1;       // dead past k>=6
                    if (k < 6) {
                        const char* rp = ldsT + (rowbase + coff[k + 2]);
                        e0 = *(const float4*)rp;
                        e1 = *(const float4*)(rp + ROWB);
                    }
                    if (k > 0 || w > 0) {          // scan j=0 is empty: skip on wave 0
                        rot_pk((f2){c0.x, c0.y}, (f2){c0.z, c0.w}, V0, A[k]);
                        rot_pk((f2){c1.x, c1.y}, (f2){c1.z, c1.w}, V1, A[k]);
                    }
                    c0 = d0; c1 = d1; d0 = e0; d1 = e1;
                }

                // ---- pass pair to next band / emit real parts ----
                if (w < NW - 1) {
                    pipe[w][q & 1][c] = make_float4(V0.x, V0.y, V1.x, V1.y);
                } else {
                    const long long oidx = obase + (long long)i0 * RANK + c;
                    if (oidx < out_limit)        out[oidx]        = V0.x;
                    if (oidx + RANK < out_limit) out[oidx + RANK] = V1.x;
                }
            }
        }
    }
}

extern "C" void kernel_launch(void* const* d_in, const int* in_sizes, int n_in,
                              void* d_out, int out_size, void* d_ws, size_t ws_size,
                              hipStream_t stream)
{
    const float* theta = (const float*)d_in[0];
    float* out = (float*)d_out;
    const int batch = in_sizes[0] / (2 * N0);        // 1024 for this problem
    if (batch <= 0) return;

    stiefel_pipe<<<batch, 64 * NW, 0, stream>>>(theta, out, (long long)out_size);
}

// Round 5
// 470.634 us; speedup vs baseline: 1.5011x; 1.5011x over previous
//
#include <hip/hip_runtime.h>

typedef float f2 __attribute__((ext_vector_type(2)));

#define DIM   256
#define RANK  64
#define NSEG0 192                 // dim - rank = shortest segment
#define N0    14304               // sum_{j=0}^{63} (192+j) complex pairs per batch
#define NW    8                   // waves per block (scan bands of 8)
#define TILE  8                   // rows per staged trig tile
#define NBUF  3                   // trig tile buffers
#define HSTEP (DIM / 2)           // 128 row-pairs
#define NMACRO 34                 // 34*4 = 136 substeps >= 135
#define ROWB  (65 * 16)           // bytes per trig row: 64 segments + identity col

// Raw barrier without vmcnt drain (R2: neutral vs __syncthreads, kept so the
// theta prefetch can stay in flight). lgkmcnt(0) orders LDS write->bar->read.
#define BAR() asm volatile("s_waitcnt lgkmcnt(0)\n\ts_barrier" ::: "memory")

// Complex Givens-with-phase rotation, 8 packed VOP3P ops, no predication.
// Predication/deposit/dead-row behavior is encoded in the trig VALUES:
//   (ct,st,er,ei) = real trig     -> rotation
//   (1, 0, 1, 0)                  -> V'=A, A'=V      (deposit row, bit-exact)
//   (0,-1, 1, 0)                  -> V'=V, A'=-A     (identity; A never read)
__device__ __forceinline__ void rot_pk(const f2 qts, const f2 qps, f2& V, f2& A)
{
    f2 t1, u, t2, pp, t3, t4;
    asm("v_pk_mul_f32 %0, %1, %2 op_sel:[0,0] op_sel_hi:[0,1]"
        : "=v"(t1) : "v"(qts), "v"(A));
    asm("v_pk_fma_f32 %0, %1, %2, %3 op_sel:[1,0,0] op_sel_hi:[1,1,1] neg_lo:[1,0,0] neg_hi:[1,0,0]"
        : "=v"(u) : "v"(qts), "v"(V), "v"(t1));
    asm("v_pk_mul_f32 %0, %1, %2 op_sel:[0,0] op_sel_hi:[0,1]"
        : "=v"(t2) : "v"(qts), "v"(V));
    asm("v_pk_fma_f32 %0, %1, %2, %3 op_sel:[1,0,0] op_sel_hi:[1,1,1]"
        : "=v"(pp) : "v"(qts), "v"(A), "v"(t2));
    asm("v_pk_mul_f32 %0, %1, %2 op_sel:[0,0] op_sel_hi:[0,1]"
        : "=v"(t3) : "v"(qps), "v"(u));
    asm("v_pk_fma_f32 %0, %1, %2, %3 op_sel:[1,1,0] op_sel_hi:[1,0,1] neg_hi:[0,1,0]"
        : "=v"(V) : "v"(qps), "v"(u), "v"(t3));
    asm("v_pk_mul_f32 %0, %1, %2 op_sel:[0,0] op_sel_hi:[0,1]"
        : "=v"(t4) : "v"(qps), "v"(pp));
    asm("v_pk_fma_f32 %0, %1, %2, %3 op_sel:[1,1,0] op_sel_hi:[1,0,1] neg_lo:[0,1,0]"
        : "=v"(A) : "v"(qps), "v"(pp), "v"(t4));
}

// launch_bounds(512, 7): VGPR cap 73 (not 64) — R4 post-mortem: at cap 64 the
// allocator SPILLS pipeline registers to scratch (FETCH 62->510 MB, +57% time)
// rather than exceed the bound. Depth-1 pipeline demand ~60 VGPR; worst case
// compiler uses 65-73 and occupancy drops 4->3 blocks/CU (mild), spill is
// structurally impossible.
__global__ __launch_bounds__(64 * NW, 7)
void stiefel_pipe(const float* __restrict__ theta, float* __restrict__ out,
                  long long out_limit)
{
    const int b   = blockIdx.x;
    const int tid = threadIdx.x;
    const int w   = __builtin_amdgcn_readfirstlane(tid >> 6);  // band 0..7 (SGPR)
    const int c   = tid & 63;                                  // column lane

    const float2* tb = (const float2*)theta + (size_t)b * N0;  // (t,p) pairs
    const long long obase = (long long)b * (DIM * RANK);

    // 3*8*65*16 = 24960 B  +  7*2*64*16 = 14336 B  -> 39296 B (4 blocks/CU)
    __shared__ float4 trigT[NBUF][TILE][65];
    __shared__ float4 pipe[NW - 1][2][64];    // [boundary][pair parity][col] = {V0,V1}

    const int jbase = 8 * w;

    f2 A[8];
    #pragma unroll
    for (int k = 0; k < 8; ++k) A[k] = (f2){0.f, 0.f};

    // per-lane trig column byte offsets; identity col 64 for inactive (lane,scan)
    int coff[8];
    #pragma unroll
    for (int k = 0; k < 8; ++k) {
        const int j = jbase + k;
        coff[k] = ((c >= 64 - j) ? j : 64) << 4;
    }

    // staging ownership: thread -> (row rS of tile, segment jS); 512 thr = 8x64
    const int jS   = c;
    const int rS   = w;
    const int offS = NSEG0 * jS + ((jS * (jS - 1)) >> 1);
    const int lenS = NSEG0 + jS;

    // identity column: content never changes, init all buffers once
    if (tid < NBUF * TILE) {
        trigT[tid / TILE][tid % TILE][64] = make_float4(0.f, -1.f, 1.f, 0.f);
    }

    // rowJ generator state (band 0; lane c <-> segment 63-c)
    const int gseg = 63 - c;
    float S = 1.f, Er = 1.f, Ei = 0.f;

    // prefetch theta for tile 0 (row rS < 192 always valid)
    float2 pf = tb[offS + rS];

    const char* ldsT = (const char*)trigT;

    #pragma unroll 1
    for (int Sm = 0; Sm < NMACRO; ++Sm) {
        // ---- stage one 8-row trig tile per macro-step, from prefetched regs ----
        if (Sm < 32) {
            const int i = (Sm << 3) + rS;          // global row this thread stages
            float4 val;
            if (i < lenS) {
                val = make_float4(__cosf(pf.x), __sinf(pf.x),
                                  __cosf(pf.y), __sinf(pf.y));
            } else if (i == lenS) {
                val = make_float4(1.f, 0.f, 1.f, 0.f);     // deposit row
            } else {
                val = make_float4(0.f, -1.f, 1.f, 0.f);    // dead row (identity)
            }
            trigT[Sm % NBUF][rS][jS] = val;
            const int i2 = i + TILE;               // prefetch next tile's theta
            if (i2 < lenS && Sm + 1 < 32) pf = tb[offS + i2];
        }

        #pragma unroll
        for (int u = 0; u < 4; ++u) {
            const int s = (Sm << 2) + u;
            BAR();                                 // the step boundary

            const int q = s - w;                   // this band's row-pair index
            if (q >= 0 && q < HSTEP) {
                const int i0 = q << 1;             // even row of the pair
                const int rowbase =
                    ((((i0 >> 3) % NBUF) * TILE + (i0 & 7))) * ROWB;

                // ---- entry-value loads (longest chain) issued first ----
                f2 V0, V1;
                if (w == 0) {
                    const char* gp = ldsT + (rowbase + (gseg << 4));
                    const float4 g0 = *(const float4*)gp;
                    const float4 g1 = *(const float4*)(gp + ROWB);
                    {   // row i0
                        const float Fr = Er * g0.z + Ei * g0.w;   // E * conj(e_i)
                        const float Fi = Ei * g0.z - Er * g0.w;
                        const float amp = g0.x * S;
                        V0 = (f2){amp * Fr, amp * Fi};
                        S *= g0.y;
                        const float nEr = Er * g0.z - Ei * g0.w;  // E *= e_i
                        const float nEi = Ei * g0.z + Er * g0.w;
                        Er = nEr; Ei = nEi;
                    }
                    {   // row i0+1
                        const float Fr = Er * g1.z + Ei * g1.w;
                        const float Fi = Ei * g1.z - Er * g1.w;
                        const float amp = g1.x * S;
                        V1 = (f2){amp * Fr, amp * Fi};
                        S *= g1.y;
                        const float nEr = Er * g1.z - Ei * g1.w;
                        const float nEi = Ei * g1.z + Er * g1.w;
                        Er = nEr; Ei = nEi;
                    }
                } else {
                    const float4 pv = pipe[w - 1][q & 1][c];
                    V0 = (f2){pv.x, pv.y};
                    V1 = (f2){pv.z, pv.w};
                }

                // ---- 8 scans x 2 rows, trig loads pipelined ONE scan ahead
                //      (depth-1: 4 live float4 = 16 VGPR, vs R4's spilling 24) ----
                const char* a0 = ldsT + (rowbase + coff[0]);
                float4 c0 = *(const float4*)a0;            // scan k   row i0
                float4 c1 = *(const float4*)(a0 + ROWB);   // scan k   row i0+1

                #pragma unroll
                for (int k = 0; k < 8; ++k) {
                    float4 n0 = c0, n1 = c1;
                    if (k < 7) {
                        const char* ak = ldsT + (rowbase + coff[k + 1]);
                        n0 = *(const float4*)ak;
                        n1 = *(const float4*)(ak + ROWB);
                    }
                    if (k > 0 || w > 0) {          // scan j=0 is empty: skip on wave 0
                        rot_pk((f2){c0.x, c0.y}, (f2){c0.z, c0.w}, V0, A[k]);
                        rot_pk((f2){c1.x, c1.y}, (f2){c1.z, c1.w}, V1, A[k]);
                    }
                    c0 = n0; c1 = n1;
                }

                // ---- pass pair to next band / emit real parts ----
                if (w < NW - 1) {
                    pipe[w][q & 1][c] = make_float4(V0.x, V0.y, V1.x, V1.y);
                } else {
                    const long long oidx = obase + (long long)i0 * RANK + c;
                    if (oidx < out_limit)        out[oidx]        = V0.x;
                    if (oidx + RANK < out_limit) out[oidx + RANK] = V1.x;
                }
            }
        }
    }
}

extern "C" void kernel_launch(void* const* d_in, const int* in_sizes, int n_in,
                              void* d_out, int out_size, void* d_ws, size_t ws_size,
                              hipStream_t stream)
{
    const float* theta = (const float*)d_in[0];
    float* out = (float*)d_out;
    const int batch = in_sizes[0] / (2 * N0);        // 1024 for this problem
    if (batch <= 0) return;

    stiefel_pipe<<<batch, 64 * NW, 0, stream>>>(theta, out, (long long)out_size);
}

// Round 6
// 455.390 us; speedup vs baseline: 1.5513x; 1.0335x over previous
//
#include <hip/hip_runtime.h>

typedef float f2 __attribute__((ext_vector_type(2)));

#define DIM   256
#define RANK  64
#define NSEG0 192                 // dim - rank = shortest segment
#define N0    14304               // sum_{j=0}^{63} (192+j) complex pairs per batch
#define NW    8                   // waves per block (scan bands of 8)
#define TILE  8                   // rows per staged trig tile
#define NBUF  3                   // trig tile buffers
#define HSTEP (DIM / 2)           // 128 row-pairs
#define NMACRO 34                 // 34*4 = 136 substeps >= 135
#define ROWB  (64 * 16)           // bytes per trig row (identity column REMOVED)

// Raw barrier without vmcnt drain (R2: neutral vs __syncthreads, kept so the
// theta prefetch can stay in flight). lgkmcnt(0) orders LDS write->bar->read.
#define BAR() asm volatile("s_waitcnt lgkmcnt(0)\n\ts_barrier" ::: "memory")

// Complex Givens-with-phase rotation, 8 packed VOP3P ops.
// Row-state behavior is encoded in the trig VALUES staged per (row, seg):
//   (ct,st,er,ei) = real trig     -> rotation
//   (1, 0, 1, 0)                  -> V'=A, A'=V      (deposit row, bit-exact)
//   (0,-1, 1, 0)                  -> V'=V, A'=-A     (dead row; A dead too)
// Lane inactivity (c < 64-j) is now an EXEC guard at the call site: skipped
// lanes leave V and A untouched — bit-identical to the old identity-column
// path (which left V unchanged and only harmlessly sign-flipped dead A).
__device__ __forceinline__ void rot_pk(const f2 qts, const f2 qps, f2& V, f2& A)
{
    f2 t1, u, t2, pp, t3, t4;
    asm("v_pk_mul_f32 %0, %1, %2 op_sel:[0,0] op_sel_hi:[0,1]"
        : "=v"(t1) : "v"(qts), "v"(A));
    asm("v_pk_fma_f32 %0, %1, %2, %3 op_sel:[1,0,0] op_sel_hi:[1,1,1] neg_lo:[1,0,0] neg_hi:[1,0,0]"
        : "=v"(u) : "v"(qts), "v"(V), "v"(t1));
    asm("v_pk_mul_f32 %0, %1, %2 op_sel:[0,0] op_sel_hi:[0,1]"
        : "=v"(t2) : "v"(qts), "v"(V));
    asm("v_pk_fma_f32 %0, %1, %2, %3 op_sel:[1,0,0] op_sel_hi:[1,1,1]"
        : "=v"(pp) : "v"(qts), "v"(A), "v"(t2));
    asm("v_pk_mul_f32 %0, %1, %2 op_sel:[0,0] op_sel_hi:[0,1]"
        : "=v"(t3) : "v"(qps), "v"(u));
    asm("v_pk_fma_f32 %0, %1, %2, %3 op_sel:[1,1,0] op_sel_hi:[1,0,1] neg_hi:[0,1,0]"
        : "=v"(V) : "v"(qps), "v"(u), "v"(t3));
    asm("v_pk_mul_f32 %0, %1, %2 op_sel:[0,0] op_sel_hi:[0,1]"
        : "=v"(t4) : "v"(qps), "v"(pp));
    asm("v_pk_fma_f32 %0, %1, %2, %3 op_sel:[1,1,0] op_sel_hi:[1,0,1] neg_lo:[0,1,0]"
        : "=v"(A) : "v"(qps), "v"(pp), "v"(t4));
}

// launch_bounds(512, 7): VGPR cap 73 — R4 showed cap 64 makes the allocator
// SPILL to scratch (FETCH 62->510 MB, +57%). Demand here ~40 VGPR; no spill.
__global__ __launch_bounds__(64 * NW, 7)
void stiefel_pipe(const float* __restrict__ theta, float* __restrict__ out,
                  long long out_limit)
{
    const int b   = blockIdx.x;
    const int tid = threadIdx.x;
    const int w   = __builtin_amdgcn_readfirstlane(tid >> 6);  // band 0..7 (SGPR)
    const int c   = tid & 63;                                  // column lane

    const float2* tb = (const float2*)theta + (size_t)b * N0;  // (t,p) pairs
    const long long obase = (long long)b * (DIM * RANK);

    // 3*8*64*16 = 24576 B  +  7*2*64*16 = 14336 B  -> 38912 B (4 blocks/CU)
    __shared__ float4 trigT[NBUF][TILE][64];
    __shared__ float4 pipe[NW - 1][2][64];    // [boundary][pair parity][col] = {V0,V1}

    const int jbase = 8 * w;

    f2 A[8];
    #pragma unroll
    for (int k = 0; k < 8; ++k) A[k] = (f2){0.f, 0.f};

    // hoisted per-scan activity predicates (v_cmp once, SGPR-pair masks)
    bool act[8];
    #pragma unroll
    for (int k = 0; k < 8; ++k) act[k] = (c >= 64 - (jbase + k));  // j=0 -> none

    // staging ownership: thread -> (row rS of tile, segment jS); 512 thr = 8x64
    const int jS   = c;
    const int rS   = w;
    const int offS = NSEG0 * jS + ((jS * (jS - 1)) >> 1);
    const int lenS = NSEG0 + jS;

    // rowJ generator state (band 0; lane c <-> segment 63-c)
    const int gseg = 63 - c;
    float S = 1.f, Er = 1.f, Ei = 0.f;

    // prefetch theta for tile 0 (row rS < 192 always valid)
    float2 pf = tb[offS + rS];

    const char* ldsT = (const char*)trigT;

    #pragma unroll 1
    for (int Sm = 0; Sm < NMACRO; ++Sm) {
        // ---- stage one 8-row trig tile per macro-step, from prefetched regs ----
        if (Sm < 32) {
            const int i = (Sm << 3) + rS;          // global row this thread stages
            float4 val;
            if (i < lenS) {
                val = make_float4(__cosf(pf.x), __sinf(pf.x),
                                  __cosf(pf.y), __sinf(pf.y));
            } else if (i == lenS) {
                val = make_float4(1.f, 0.f, 1.f, 0.f);     // deposit row
            } else {
                val = make_float4(0.f, -1.f, 1.f, 0.f);    // dead row
            }
            trigT[Sm % NBUF][rS][jS] = val;
            const int i2 = i + TILE;               // prefetch next tile's theta
            if (i2 < lenS && Sm + 1 < 32) pf = tb[offS + i2];
        }

        #pragma unroll
        for (int u = 0; u < 4; ++u) {
            const int s = (Sm << 2) + u;
            BAR();                                 // the step boundary

            const int q = s - w;                   // this band's row-pair index
            if (q >= 0 && q < HSTEP) {
                const int i0 = q << 1;             // even row of the pair
                const int rowbase =
                    ((((i0 >> 3) % NBUF) * TILE + (i0 & 7))) * ROWB;

                // ---- values entering this band (2 rows) ----
                f2 V0, V1;
                if (w == 0) {
                    const char* gp = ldsT + (rowbase + (gseg << 4));
                    const float4 g0 = *(const float4*)gp;
                    const float4 g1 = *(const float4*)(gp + ROWB);
                    {   // row i0
                        const float Fr = Er * g0.z + Ei * g0.w;   // E * conj(e_i)
                        const float Fi = Ei * g0.z - Er * g0.w;
                        const float amp = g0.x * S;
                        V0 = (f2){amp * Fr, amp * Fi};
                        S *= g0.y;
                        const float nEr = Er * g0.z - Ei * g0.w;  // E *= e_i
                        const float nEi = Ei * g0.z + Er * g0.w;
                        Er = nEr; Ei = nEi;
                    }
                    {   // row i0+1
                        const float Fr = Er * g1.z + Ei * g1.w;
                        const float Fi = Ei * g1.z - Er * g1.w;
                        const float amp = g1.x * S;
                        V1 = (f2){amp * Fr, amp * Fi};
                        S *= g1.y;
                        const float nEr = Er * g1.z - Ei * g1.w;
                        const float nEi = Ei * g1.z + Er * g1.w;
                        Er = nEr; Ei = nEi;
                    }
                } else {
                    const float4 pv = pipe[w - 1][q & 1][c];
                    V0 = (f2){pv.x, pv.y};
                    V1 = (f2){pv.z, pv.w};
                }

                // ---- 8 scans x 2 rows: UNIFORM-address trig (true broadcast,
                //      one address reg, rows via offset:+1024), exec-guarded ----
                #pragma unroll
                for (int k = 0; k < 8; ++k) {
                    if (act[k]) {
                        const char* rp = ldsT + (rowbase + ((jbase + k) << 4));
                        const float4 q0 = *(const float4*)rp;
                        const float4 q1 = *(const float4*)(rp + ROWB);
                        rot_pk((f2){q0.x, q0.y}, (f2){q0.z, q0.w}, V0, A[k]);
                        rot_pk((f2){q1.x, q1.y}, (f2){q1.z, q1.w}, V1, A[k]);
                    }
                }

                // ---- pass pair to next band / emit real parts ----
                if (w < NW - 1) {
                    pipe[w][q & 1][c] = make_float4(V0.x, V0.y, V1.x, V1.y);
                } else {
                    const long long oidx = obase + (long long)i0 * RANK + c;
                    if (oidx < out_limit)        out[oidx]        = V0.x;
                    if (oidx + RANK < out_limit) out[oidx + RANK] = V1.x;
                }
            }
        }
    }
}

extern "C" void kernel_launch(void* const* d_in, const int* in_sizes, int n_in,
                              void* d_out, int out_size, void* d_ws, size_t ws_size,
                              hipStream_t stream)
{
    const float* theta = (const float*)d_in[0];
    float* out = (float*)d_out;
    const int batch = in_sizes[0] / (2 * N0);        // 1024 for this problem
    if (batch <= 0) return;

    stiefel_pipe<<<batch, 64 * NW, 0, stream>>>(theta, out, (long long)out_size);
}